// Round 1
// baseline (340.977 us; speedup 1.0000x reference)
//
#include <hip/hip_runtime.h>

// Problem constants (B, F, V, D) = (16384, 16, 300000, 10)
#define Bsz   16384
#define Fn    16
#define Vn    300000
#define Dn    10
#define OUT_ROW 1376        // 120*10 + 16*10 + 16
#define ROWS_PER_BLOCK 4    // one wave per row, zero LDS

typedef float f32x2 __attribute__((ext_vector_type(2)));

// triu(k=1) pair table, row-major order, packed i*16+j
__device__ const unsigned char PAIR_IJ[120] = {
    1,2,3,4,5,6,7,8,9,10,11,12,13,14,15,
    18,19,20,21,22,23,24,25,26,27,28,29,30,31,
    35,36,37,38,39,40,41,42,43,44,45,46,47,
    52,53,54,55,56,57,58,59,60,61,62,63,
    69,70,71,72,73,74,75,76,77,78,79,
    86,87,88,89,90,91,92,93,94,95,
    103,104,105,106,107,108,109,110,111,
    120,121,122,123,124,125,126,127,
    137,138,139,140,141,142,143,
    154,155,156,157,158,159,
    171,172,173,174,175,
    188,189,190,191,
    205,206,207,
    222,223,
    239
};

// RULE (R1+R3): every __shfl executes with all 64 lanes converged.
// launch_bounds(256,6): cap ~84 VGPR -> 24 waves/CU; full-unroll MLP is the lever.
// R4: output is write-once, never re-read -> non-temporal stores so the 88 MB
//     write stream does not evict the 192 MB emb table from L2/Infinity-Cache.
__global__ __launch_bounds__(256, 6) void ffm_kernel(
    const int*   __restrict__ x,     // (B, F)
    const float* __restrict__ emb,   // (F, V, D)
    const float* __restrict__ lin,   // (V, 1)
    float*       __restrict__ out)   // (B, OUT_ROW)
{
    const int wave = threadIdx.x >> 6;
    const int lane = threadIdx.x & 63;
    const int row  = blockIdx.x * ROWS_PER_BLOCK + wave;

    const int xv = x[row * Fn + (lane & 15)];   // lane 16a+f holds x[row,f]
    float* orow = out + (size_t)row * OUT_ROW;
    const float lv = lin[xv];                   // converged; lanes 16..31 store it

    // ---- tail operands (cols 1280..1359, self region), computed CONVERGED ----
    // k0t = 1280 + 2*lane; lanes 0..39 cover the 80 floats
    const int k0t = 1280 + 2 * lane;
    const int pt  = k0t / 10;                   // 128..140 across lanes
    const int d0t = k0t - pt * 10;              // even
    const int ft  = pt - 120;                   // 8..20; only <16 is real
    const int fts = (ft < 16) ? ft : 0;         // clamp shuffle src (lanes 40+ unused)
    const int xft = __shfl(xv, fts);            // CONVERGED
    float2 tailv = make_float2(0.f, 0.f);
    if (lane < 40) {                            // load under divergence is fine
        tailv = *(const float2*)(emb + (unsigned)(fts * Vn + xft) * 10u + d0t);
    }

    // ---- main: k0 = 2*lane + 128*it, it=0..9 covers cols 0..1279 ----
    // it<=8 pure pair region; it=9 mixes pair (p<120) and self (p>=120).
    // Issue ALL 20 dwordx2 loads before any store (MLP).
    float2 A[10], Bv[10];
    bool   pr[10];
    #pragma unroll
    for (int it = 0; it < 10; ++it) {
        const int k0 = 2 * lane + (it << 7);
        const int p  = k0 / 10;                 // magic-mul
        const int d0 = k0 - p * 10;             // even
        const bool isPair = p < 120;
        pr[it] = isPair;
        const int ij = PAIR_IJ[isPair ? p : 0];
        const int f  = p - 120;                 // 0..7 when self (it=9 only)
        const int i  = isPair ? (ij >> 4) : f;
        const int j  = isPair ? (ij & 15) : f;
        const int xi = __shfl(xv, i);           // CONVERGED
        const int xj = __shfl(xv, j);           // CONVERGED
        A[it]  = *(const float2*)(emb + (unsigned)(j * Vn + xi) * 10u + d0);
        Bv[it] = *(const float2*)(emb + (unsigned)(i * Vn + xj) * 10u + d0);
    }
    #pragma unroll
    for (int it = 0; it < 10; ++it) {
        const int k0 = 2 * lane + (it << 7);
        f32x2 r;
        r.x = pr[it] ? A[it].x * Bv[it].x : A[it].x;
        r.y = pr[it] ? A[it].y * Bv[it].y : A[it].y;
        __builtin_nontemporal_store(r, (f32x2*)(orow + k0));
    }

    // ---- tail stores ----
    if (lane < 40) {
        f32x2 tv; tv.x = tailv.x; tv.y = tailv.y;
        __builtin_nontemporal_store(tv, (f32x2*)(orow + k0t)); // cols 1280..1359
    }
    if (lane >= 16 && lane < 32) {
        __builtin_nontemporal_store(lv, orow + 1344 + lane);   // cols 1360..1375
    }
}

extern "C" void kernel_launch(void* const* d_in, const int* in_sizes, int n_in,
                              void* d_out, int out_size, void* d_ws, size_t ws_size,
                              hipStream_t stream) {
    const int*   x   = (const int*)d_in[0];
    const float* emb = (const float*)d_in[1];
    const float* lin = (const float*)d_in[2];
    float*       out = (float*)d_out;

    const int blocks = Bsz / ROWS_PER_BLOCK;   // 4096
    ffm_kernel<<<blocks, 256, 0, stream>>>(x, emb, lin, out);
}

// Round 2
// 340.698 us; speedup vs baseline: 1.0008x; 1.0008x over previous
//
#include <hip/hip_runtime.h>

// Problem constants (B, F, V, D) = (16384, 16, 300000, 10)
#define Bsz   16384
#define Fn    16
#define Vn    300000
#define Dn    10
#define OUT_ROW 1376        // 120*10 + 16*10 + 16
#define ROWS_PER_BLOCK 4    // one wave per row

typedef float f32x2 __attribute__((ext_vector_type(2)));

// triu(k=1) pair table, row-major order, packed i*16+j
__device__ const unsigned char PAIR_IJ[120] = {
    1,2,3,4,5,6,7,8,9,10,11,12,13,14,15,
    18,19,20,21,22,23,24,25,26,27,28,29,30,31,
    35,36,37,38,39,40,41,42,43,44,45,46,47,
    52,53,54,55,56,57,58,59,60,61,62,63,
    69,70,71,72,73,74,75,76,77,78,79,
    86,87,88,89,90,91,92,93,94,95,
    103,104,105,106,107,108,109,110,111,
    120,121,122,123,124,125,126,127,
    137,138,139,140,141,142,143,
    154,155,156,157,158,159,
    171,172,173,174,175,
    188,189,190,191,
    205,206,207,
    222,223,
    239
};

// Async gather of one dword per lane directly into LDS (no VGPR cost).
// LDS dst rule: HW writes wave-uniform base + lane*4 -> pass the uniform
// per-it base; our LDS layout is linear in output column k = 64*it + lane.
__device__ __forceinline__ void gload_lds4(const float* g, void* l) {
    __builtin_amdgcn_global_load_lds(
        (const __attribute__((address_space(1))) void*)g,
        (__attribute__((address_space(3))) void*)l, 4, 0, 0);
}

// RULE (R1+R3): every __shfl executes with all 64 lanes converged.
// R5 (this round): B-operand gathers go global->LDS via global_load_lds so a
// wave keeps ~30 loads in flight while holding only the 10 A float2s in VGPR.
// LDS 4*5120 B = 20480 B/block -> exactly 8 blocks/CU; launch_bounds(256,8)
// caps VGPR at 64 -> 32 waves/CU target (vs ~23 before).
__global__ __launch_bounds__(256, 8) void ffm_kernel(
    const int*   __restrict__ x,     // (B, F)
    const float* __restrict__ emb,   // (F, V, D)
    const float* __restrict__ lin,   // (V, 1)
    float*       __restrict__ out)   // (B, OUT_ROW)
{
    __shared__ float smemB[ROWS_PER_BLOCK][1280];   // B operand by output col

    const int wave = threadIdx.x >> 6;
    const int lane = threadIdx.x & 63;
    const int row  = blockIdx.x * ROWS_PER_BLOCK + wave;

    const int xv = x[row * Fn + (lane & 15)];   // lane 16a+f holds x[row,f]
    float* orow = out + (size_t)row * OUT_ROW;
    const float lv = lin[xv];                   // converged; lanes 16..31 store it

    // pair table distributed across lanes (2 ubyte loads replace 29 gathers);
    // ij for p: p<64 -> shfl(ijlo,p), else shfl(ijhi,p-64). p in [120,128) is
    // clamped garbage but only read when isPair==false.
    const int ijlo = PAIR_IJ[lane];                       // p = 0..63
    const int ijhi = PAIR_IJ[lane < 56 ? 64 + lane : 0];  // p = 64..119

    // ---- B gathers -> LDS. Cols 0..1199 are pair region (B exists). ----
    // it=18 is partial (lanes 48..63 are self cols); it=19 would be all-self.
    #pragma unroll
    for (int it = 0; it < 19; ++it) {
        const int k = lane + (it << 6);
        const unsigned p = ((unsigned)k * 52429u) >> 19;   // k/10
        const int d  = k - 10 * (int)p;
        const int ij = (p < 64) ? __shfl(ijlo, (int)p) : __shfl(ijhi, (int)p - 64);
        const bool isPair = p < 120;
        const int f  = (int)p - 120;
        const int i  = isPair ? (ij >> 4) : f;
        const int j  = isPair ? (ij & 15) : f;
        const int xj = __shfl(xv, j);           // CONVERGED (before the mask)
        if (k < 1200) {
            gload_lds4(emb + (unsigned)(i * Vn + xj) * 10u + d,
                       (void*)&smemB[wave][it << 6]);
        }
    }

    // ---- A gathers (float2 per lane, held in VGPR) ----
    float2 A[10];
    bool   prm[10];
    #pragma unroll
    for (int it = 0; it < 10; ++it) {
        const int k0 = 2 * lane + (it << 7);
        const unsigned p = ((unsigned)k0 * 52429u) >> 19;  // k0/10
        const int d0 = k0 - 10 * (int)p;
        const bool isPair = p < 120;
        prm[it] = isPair;
        const int ij = (p < 64) ? __shfl(ijlo, (int)p) : __shfl(ijhi, (int)p - 64);
        const int f  = (int)p - 120;
        const int i  = isPair ? (ij >> 4) : f;
        const int j  = isPair ? (ij & 15) : f;
        const int xi = __shfl(xv, i);           // CONVERGED
        A[it] = *(const float2*)(emb + (unsigned)(j * Vn + xi) * 10u + d0);
    }

    // ---- tail operands (cols 1280..1359, self region), CONVERGED ----
    const int k0t = 1280 + 2 * lane;
    const int pt  = k0t / 10;                   // 128..140 across lanes
    const int d0t = k0t - pt * 10;              // even
    const int ft  = pt - 120;                   // 8..20; only <16 is real
    const int fts = (ft < 16) ? ft : 0;
    const int xft = __shfl(xv, fts);            // CONVERGED
    float2 tailv = make_float2(0.f, 0.f);
    if (lane < 40) {
        tailv = *(const float2*)(emb + (unsigned)(fts * Vn + xft) * 10u + d0t);
    }

    // Drain all global_load_lds writes (vmcnt) before reading LDS.
    __syncthreads();

    // ---- multiply & store ----
    #pragma unroll
    for (int it = 0; it < 10; ++it) {
        const int k0 = 2 * lane + (it << 7);
        const float2 b = *(const float2*)&smemB[wave][(it << 7) + 2 * lane];
        f32x2 r;
        r.x = prm[it] ? A[it].x * b.x : A[it].x;
        r.y = prm[it] ? A[it].y * b.y : A[it].y;
        __builtin_nontemporal_store(r, (f32x2*)(orow + k0));
    }

    // ---- tail stores ----
    if (lane < 40) {
        f32x2 tv; tv.x = tailv.x; tv.y = tailv.y;
        __builtin_nontemporal_store(tv, (f32x2*)(orow + k0t)); // cols 1280..1359
    }
    if (lane >= 16 && lane < 32) {
        __builtin_nontemporal_store(lv, orow + 1344 + lane);   // cols 1360..1375
    }
}

extern "C" void kernel_launch(void* const* d_in, const int* in_sizes, int n_in,
                              void* d_out, int out_size, void* d_ws, size_t ws_size,
                              hipStream_t stream) {
    const int*   x   = (const int*)d_in[0];
    const float* emb = (const float*)d_in[1];
    const float* lin = (const float*)d_in[2];
    float*       out = (float*)d_out;

    const int blocks = Bsz / ROWS_PER_BLOCK;   // 4096
    ffm_kernel<<<blocks, 256, 0, stream>>>(x, emb, lin, out);
}